// Round 7
// baseline (391.809 us; speedup 1.0000x reference)
//
#include <hip/hip_runtime.h>
#include <hip/hip_bf16.h>
#include <cmath>

// ---------------------------------------------------------------------------
// StackAttCore: 3x LSTM + 2x additive attention. B=256 L=196 R=1024 A=512 E=1024
// Round 7: LSTM GEMM -> 128x64 tile (halves W re-fetch, 48KB LDS, 3 blk/CU);
// attention back to R5's high-occupancy scores+smw split.
// ---------------------------------------------------------------------------

#define B_ 256
#define L_ 196
#define R_ 1024
#define A_ 512
#define E_ 1024

typedef __attribute__((ext_vector_type(8))) short bf16x8;
typedef __attribute__((ext_vector_type(4))) float f32x4;

__device__ inline ushort f2bf(float f) {
  __hip_bfloat16 h = __float2bfloat16(f);
  return *(ushort*)&h;
}
__device__ inline uint pk2bf(float lo, float hi) {
  float2 t; t.x = lo; t.y = hi;
  __hip_bfloat162 h = __float22bfloat162_rn(t);
  return *(uint*)&h;
}
__device__ inline float ftanh(float x) {
  float e = __expf(2.f * x);
  return 1.f - 2.f / (e + 1.f);
}

// ---------------------------------------------------------------------------
// LSTM GEMM: tile 128x64, BK=64, 4 waves (2m x 2n), 16x16x32 MFMA.
// Cpart[z][M,N] = Xb(bf16)[M,k0:k0+Ks] @ [W1|W2](fp32->bf16)[N,k0:k0+Ks]^T
// Only 2 m-blocks -> W re-fetch halves vs 64-wide tiles. LDS 48KB -> 3 blk/CU.
// XCD-grouped decode: the 2 m-blocks of each (n0,z) W-group -> same XCD.
// ---------------------------------------------------------------------------
__global__ __launch_bounds__(256) void gemm_m128(
    float* __restrict__ C, int ldc, size_t pstride,
    const ushort* __restrict__ Xb, int ldx,
    const float* __restrict__ W1, int ldw1, int K1,
    const float* __restrict__ W2, int ldw2,
    int K, int nbn, int ns)
{
  __shared__ ushort lA[2][128 * 64];
  __shared__ ushort lB[2][64 * 64];
  const int tid = threadIdx.x;

  const int flat = blockIdx.x;
  const int xcd = flat & 7;
  const int j = flat >> 3;
  const int mB = j & 1;
  const int group = (j >> 1) * 8 + xcd;   // 0 .. nbn*ns-1
  const int n0 = (group % nbn) * 64;
  const int z  = group / nbn;
  const int m0 = mB * 128;

  const int Ks = K / ns;
  const int k0 = z * Ks;
  C += (size_t)z * pstride;

  // A staging: 1024 chunks of 16B (128 rows x 8 kslots); 4 chunks/thread
  int arow[4], aks[4], awz[4];
#pragma unroll
  for (int i = 0; i < 4; i++) {
    int c = i * 256 + tid;
    arow[i] = c >> 3;
    aks[i] = c & 7;
    awz[i] = arow[i] * 64 + ((aks[i] ^ (arow[i] & 7)) * 8);
  }
  // B staging: row = tid>>2 (0..63), quarter = tid&3 (16 fp32)
  const int brow = tid >> 2;
  const int bq = tid & 3;
  const int bwz0 = brow * 64 + (((bq * 2) ^ (brow & 7)) * 8);
  const int bwz1 = brow * 64 + (((bq * 2 + 1) ^ (brow & 7)) * 8);

  const int lane = tid & 63;
  const int wid = tid >> 6;
  const int wr = wid >> 1, wc = wid & 1;     // wave: 64 rows x 32 cols
  const int l15 = lane & 15, l4 = lane >> 4;
  int aoff[4][2], boff[2][2];
#pragma unroll
  for (int m = 0; m < 4; m++)
#pragma unroll
    for (int s = 0; s < 2; s++) {
      int ra = wr * 64 + m * 16 + l15;
      int sl = s * 4 + l4;
      aoff[m][s] = ra * 64 + ((sl ^ (ra & 7)) * 8);
    }
#pragma unroll
  for (int n = 0; n < 2; n++)
#pragma unroll
    for (int s = 0; s < 2; s++) {
      int rb = wc * 32 + n * 16 + l15;
      int sl = s * 4 + l4;
      boff[n][s] = rb * 64 + ((sl ^ (rb & 7)) * 8);
    }

  f32x4 zero = {0.f, 0.f, 0.f, 0.f};
  f32x4 acc[4][2];
#pragma unroll
  for (int m = 0; m < 4; m++) { acc[m][0] = zero; acc[m][1] = zero; }

  uint4 ax[4];
  f32x4 bw[4];
  const int NT = Ks >> 6;

  auto g_load = [&](int kt) {
    const int kk = k0 + kt * 64;
#pragma unroll
    for (int i = 0; i < 4; i++)
      ax[i] = *(const uint4*)(Xb + (size_t)(m0 + arow[i]) * ldx + kk + aks[i] * 8);
    const float* wp;
    if (kk < K1) wp = W1 + (size_t)(n0 + brow) * ldw1 + kk + bq * 16;
    else         wp = W2 + (size_t)(n0 + brow) * ldw2 + (kk - K1) + bq * 16;
    bw[0] = *(const f32x4*)wp;
    bw[1] = *(const f32x4*)(wp + 4);
    bw[2] = *(const f32x4*)(wp + 8);
    bw[3] = *(const f32x4*)(wp + 12);
  };
  auto s_write = [&](int buf) {
#pragma unroll
    for (int i = 0; i < 4; i++) *(uint4*)&lA[buf][awz[i]] = ax[i];
    uint4 b0, b1;
    b0.x = pk2bf(bw[0].x, bw[0].y); b0.y = pk2bf(bw[0].z, bw[0].w);
    b0.z = pk2bf(bw[1].x, bw[1].y); b0.w = pk2bf(bw[1].z, bw[1].w);
    b1.x = pk2bf(bw[2].x, bw[2].y); b1.y = pk2bf(bw[2].z, bw[2].w);
    b1.z = pk2bf(bw[3].x, bw[3].y); b1.w = pk2bf(bw[3].z, bw[3].w);
    *(uint4*)&lB[buf][bwz0] = b0;
    *(uint4*)&lB[buf][bwz1] = b1;
  };
  auto compute = [&](int buf) {
#pragma unroll
    for (int s = 0; s < 2; s++) {
      bf16x8 bf0 = *(const bf16x8*)&lB[buf][boff[0][s]];
      bf16x8 bf1 = *(const bf16x8*)&lB[buf][boff[1][s]];
#pragma unroll
      for (int m = 0; m < 4; m++) {
        bf16x8 af = *(const bf16x8*)&lA[buf][aoff[m][s]];
        acc[m][0] = __builtin_amdgcn_mfma_f32_16x16x32_bf16(af, bf0, acc[m][0], 0, 0, 0);
        acc[m][1] = __builtin_amdgcn_mfma_f32_16x16x32_bf16(af, bf1, acc[m][1], 0, 0, 0);
      }
    }
  };

  g_load(0);
  s_write(0);
  __syncthreads();
  int cur = 0;
  for (int kt = 0; kt < NT; kt++) {
    if (kt + 1 < NT) g_load(kt + 1);
    compute(cur);
    if (kt + 1 < NT) s_write(cur ^ 1);
    __syncthreads();
    cur ^= 1;
  }

#pragma unroll
  for (int m = 0; m < 4; m++)
#pragma unroll
    for (int n = 0; n < 2; n++) {
      const int col = n0 + wc * 32 + n * 16 + l15;
#pragma unroll
      for (int j2 = 0; j2 < 4; j2++) {
        const int row = m0 + wr * 64 + m * 16 + l4 * 4 + j2;
        C[(size_t)row * ldc + col] = acc[m][n][j2];
      }
    }
}

// ---------------------------------------------------------------------------
// small GEMM (attH, q2): 64x64 tile, 4 waves 2x2, XCD-grouped (4 m-blocks)
// ---------------------------------------------------------------------------
__global__ __launch_bounds__(256) void gemm_mfma(
    float* __restrict__ C, int ldc, size_t pstride,
    const ushort* __restrict__ Xb, int ldx,
    const float* __restrict__ W1, int ldw1,
    int K, int nbn, int ns)
{
  __shared__ ushort lA[2][64 * 64];
  __shared__ ushort lB[2][64 * 64];
  const int tid = threadIdx.x;

  const int flat = blockIdx.x;
  const int xcd = flat & 7;
  const int j = flat >> 3;
  const int mB = j & 3;
  const int group = (j >> 2) * 8 + xcd;
  const int n0 = (group % nbn) * 64;
  const int z  = group / nbn;
  const int m0 = mB * 64;

  const int Ks = K / ns;
  const int k0 = z * Ks;
  C += (size_t)z * pstride;

  const int srow = tid >> 2;
  const int sq = tid & 3;
  const int wz0 = srow * 64 + (((sq * 2) ^ (srow & 7)) * 8);
  const int wz1 = srow * 64 + (((sq * 2 + 1) ^ (srow & 7)) * 8);

  const int lane = tid & 63;
  const int wid = tid >> 6;
  const int wr = wid >> 1, wc = wid & 1;
  const int l15 = lane & 15, l4 = lane >> 4;
  int aoff[2][2], boff[2][2];
#pragma unroll
  for (int m = 0; m < 2; m++)
#pragma unroll
    for (int s = 0; s < 2; s++) {
      int ra = wr * 32 + m * 16 + l15;
      int rb = wc * 32 + m * 16 + l15;
      int sl = s * 4 + l4;
      aoff[m][s] = ra * 64 + ((sl ^ (ra & 7)) * 8);
      boff[m][s] = rb * 64 + ((sl ^ (rb & 7)) * 8);
    }

  f32x4 zero = {0.f, 0.f, 0.f, 0.f};
  f32x4 acc[2][2];
  acc[0][0] = zero; acc[0][1] = zero; acc[1][0] = zero; acc[1][1] = zero;

  uint4 ax0, ax1;
  f32x4 bw[4];
  const int NT = Ks >> 6;

  auto g_load = [&](int kt) {
    const int kk = k0 + kt * 64;
    const ushort* ap = Xb + (size_t)(m0 + srow) * ldx + kk + sq * 16;
    ax0 = *(const uint4*)ap;
    ax1 = *(const uint4*)(ap + 8);
    const float* wp = W1 + (size_t)(n0 + srow) * ldw1 + kk + sq * 16;
    bw[0] = *(const f32x4*)wp;
    bw[1] = *(const f32x4*)(wp + 4);
    bw[2] = *(const f32x4*)(wp + 8);
    bw[3] = *(const f32x4*)(wp + 12);
  };
  auto s_write = [&](int buf) {
    *(uint4*)&lA[buf][wz0] = ax0;
    *(uint4*)&lA[buf][wz1] = ax1;
    uint4 b0, b1;
    b0.x = pk2bf(bw[0].x, bw[0].y); b0.y = pk2bf(bw[0].z, bw[0].w);
    b0.z = pk2bf(bw[1].x, bw[1].y); b0.w = pk2bf(bw[1].z, bw[1].w);
    b1.x = pk2bf(bw[2].x, bw[2].y); b1.y = pk2bf(bw[2].z, bw[2].w);
    b1.z = pk2bf(bw[3].x, bw[3].y); b1.w = pk2bf(bw[3].z, bw[3].w);
    *(uint4*)&lB[buf][wz0] = b0;
    *(uint4*)&lB[buf][wz1] = b1;
  };
  auto compute = [&](int buf) {
#pragma unroll
    for (int s = 0; s < 2; s++) {
      bf16x8 af0 = *(const bf16x8*)&lA[buf][aoff[0][s]];
      bf16x8 af1 = *(const bf16x8*)&lA[buf][aoff[1][s]];
      bf16x8 bf0 = *(const bf16x8*)&lB[buf][boff[0][s]];
      bf16x8 bf1 = *(const bf16x8*)&lB[buf][boff[1][s]];
      acc[0][0] = __builtin_amdgcn_mfma_f32_16x16x32_bf16(af0, bf0, acc[0][0], 0, 0, 0);
      acc[0][1] = __builtin_amdgcn_mfma_f32_16x16x32_bf16(af0, bf1, acc[0][1], 0, 0, 0);
      acc[1][0] = __builtin_amdgcn_mfma_f32_16x16x32_bf16(af1, bf0, acc[1][0], 0, 0, 0);
      acc[1][1] = __builtin_amdgcn_mfma_f32_16x16x32_bf16(af1, bf1, acc[1][1], 0, 0, 0);
    }
  };

  g_load(0);
  s_write(0);
  __syncthreads();
  int cur = 0;
  for (int kt = 0; kt < NT; kt++) {
    if (kt + 1 < NT) g_load(kt + 1);
    compute(cur);
    if (kt + 1 < NT) s_write(cur ^ 1);
    __syncthreads();
    cur ^= 1;
  }

#pragma unroll
  for (int m = 0; m < 2; m++)
#pragma unroll
    for (int n = 0; n < 2; n++) {
      const int col = n0 + wc * 32 + n * 16 + l15;
#pragma unroll
      for (int j2 = 0; j2 < 4; j2++) {
        const int row = m0 + wr * 32 + m * 16 + l4 * 4 + j2;
        C[(size_t)row * ldc + col] = acc[m][n][j2];
      }
    }
}

// pack 5 fp32 [256,1024] segments -> bf16 (dst row stride 3072)
__global__ __launch_bounds__(256) void pack5(
    const float* __restrict__ s0, ushort* __restrict__ d0,
    const float* __restrict__ s1, ushort* __restrict__ d1,
    const float* __restrict__ s2, ushort* __restrict__ d2,
    const float* __restrict__ s3, ushort* __restrict__ d3,
    const float* __restrict__ s4, ushort* __restrict__ d4)
{
  const int seg = blockIdx.x >> 8;
  const int row = blockIdx.x & 255;
  const int col = threadIdx.x * 4;
  const float* s;
  ushort* d;
  switch (seg) {
    case 0: s = s0; d = d0; break;
    case 1: s = s1; d = d1; break;
    case 2: s = s2; d = d2; break;
    case 3: s = s3; d = d3; break;
    default: s = s4; d = d4; break;
  }
  float4 v = *(const float4*)(s + (size_t)row * 1024 + col);
  uint2 o;
  o.x = pk2bf(v.x, v.y);
  o.y = pk2bf(v.z, v.w);
  *(uint2*)(d + (size_t)row * 3072 + col) = o;
}

// gates: sum ns partials, biases, activations -> h, c
__global__ __launch_bounds__(256) void lstm_gates(
    const float* __restrict__ Sp, int ns,
    const float* __restrict__ bi, const float* __restrict__ bh,
    const float* __restrict__ c_prev,
    float* __restrict__ h_out, float* __restrict__ c_out,
    ushort* __restrict__ hb16,
    float* __restrict__ h_out2)
{
  const int idx = blockIdx.x * 256 + threadIdx.x;
  const int b = idx >> 8;
  const int c4 = (idx & 255) * 4;
  const size_t base = (size_t)b * 5120 + c4;

  f32x4 g[5];
#pragma unroll
  for (int j = 0; j < 5; j++) g[j] = (f32x4){0.f, 0.f, 0.f, 0.f};
  for (int s = 0; s < ns; s++) {
    const float* sp = Sp + (size_t)s * 1310720 + base;
#pragma unroll
    for (int j = 0; j < 5; j++) g[j] += *(const f32x4*)(sp + j * 1024);
  }
#pragma unroll
  for (int j = 0; j < 5; j++) {
    g[j] += *(const f32x4*)(bi + j * 1024 + c4);
    g[j] += *(const f32x4*)(bh + j * 1024 + c4);
  }

  const int oidx = b * 1024 + c4;
  f32x4 cp = *(const f32x4*)(c_prev + oidx);
  f32x4 hv, cv;
#pragma unroll
  for (int i = 0; i < 4; i++) {
    float ig = 1.f / (1.f + __expf(-g[0][i]));
    float fg = 1.f / (1.f + __expf(-g[1][i]));
    float og = 1.f / (1.f + __expf(-g[2][i]));
    float it = fmaxf(g[3][i], g[4][i]);
    float c  = fg * cp[i] + ig * it;
    cv[i] = c;
    hv[i] = og * ftanh(c);
  }
  *(f32x4*)(h_out + oidx) = hv;
  *(f32x4*)(c_out + oidx) = cv;
  if (hb16) {
    uint2 o;
    o.x = pk2bf(hv[0], hv[1]);
    o.y = pk2bf(hv[2], hv[3]);
    *(uint2*)(hb16 + (size_t)b * 3072 + c4) = o;
  }
  if (h_out2) *(f32x4*)(h_out2 + oidx) = hv;
}

// scores[b,l] = sum_a tanh(p + sum_s attHp[s] + hb) * aw + ab ; wave per (b,l)
__global__ __launch_bounds__(256) void att_scores(
    float* __restrict__ scores,
    const float* __restrict__ p_att,
    const float* __restrict__ attHp, int ns,
    const float* __restrict__ hb,
    const float* __restrict__ aw,
    const float* __restrict__ ab)
{
  int wid = blockIdx.x * 4 + (threadIdx.x >> 6);
  if (wid >= B_ * L_) return;
  int lane = threadIdx.x & 63;
  int b = wid / L_;
  int l = wid % L_;
  const float* p = p_att + ((size_t)b * L_ + l) * A_;

  f32x4 q0 = {0.f, 0.f, 0.f, 0.f}, q1 = q0;
  for (int s = 0; s < ns; s++) {
    const float* qp = attHp + (size_t)s * 131072 + (size_t)b * A_ + lane * 8;
    q0 += *(const f32x4*)qp;
    q1 += *(const f32x4*)(qp + 4);
  }
  f32x4 p0 = *(const f32x4*)(p + lane * 8);
  f32x4 p1 = *(const f32x4*)(p + lane * 8 + 4);
  f32x4 h0 = *(const f32x4*)(hb + lane * 8);
  f32x4 h1 = *(const f32x4*)(hb + lane * 8 + 4);
  f32x4 w0 = *(const f32x4*)(aw + lane * 8);
  f32x4 w1 = *(const f32x4*)(aw + lane * 8 + 4);
  float part = 0.f;
#pragma unroll
  for (int i = 0; i < 4; i++) part += ftanh(p0[i] + q0[i] + h0[i]) * w0[i];
#pragma unroll
  for (int i = 0; i < 4; i++) part += ftanh(p1[i] + q1[i] + h1[i]) * w1[i];
#pragma unroll
  for (int off = 32; off > 0; off >>= 1) part += __shfl_down(part, off);
  if (lane == 0) scores[wid] = part + ab[0];
}

// fused softmax(196) + weighted sum over att_feats -> bf16 (stride 3072)
__global__ __launch_bounds__(256) void att_smw(
    ushort* __restrict__ dst,
    const float* __restrict__ sc,
    const float* __restrict__ feats)
{
  const int b = blockIdx.x >> 2;
  const int dc = blockIdx.x & 3;
  const int t = threadIdx.x;
  __shared__ float red[256];
  __shared__ float wbuf[256];

  float v = (t < L_) ? sc[b * L_ + t] : -1e30f;
  red[t] = v;
  __syncthreads();
  for (int s = 128; s > 0; s >>= 1) {
    if (t < s) red[t] = fmaxf(red[t], red[t + s]);
    __syncthreads();
  }
  float m = red[0];
  __syncthreads();
  float e = (t < L_) ? __expf(v - m) : 0.f;
  red[t] = e;
  __syncthreads();
  for (int s = 128; s > 0; s >>= 1) {
    if (t < s) red[t] += red[t + s];
    __syncthreads();
  }
  wbuf[t] = e * (1.f / red[0]);
  __syncthreads();

  const int d = dc * 256 + t;
  const float* f = feats + (size_t)b * L_ * R_ + d;
  float acc = 0.f;
#pragma unroll 4
  for (int l = 0; l < L_; l++) acc = fmaf(wbuf[l], f[(size_t)l * R_], acc);
  dst[(size_t)b * 3072 + d] = f2bf(acc);
}

// q2b(bf16,[256,1024]) = sum_s q2p[s] + h1 + emb2_b
__global__ __launch_bounds__(256) void make_q2(
    ushort* __restrict__ q2b, const float* __restrict__ q2p, int ns,
    const float* __restrict__ h1, const float* __restrict__ eb)
{
  const int idx = blockIdx.x * 256 + threadIdx.x;
  const int b = idx >> 8;
  const int c4 = (idx & 255) * 4;
  const int oidx = b * 1024 + c4;
  f32x4 a = {0.f, 0.f, 0.f, 0.f};
  for (int s = 0; s < ns; s++)
    a += *(const f32x4*)(q2p + (size_t)s * 262144 + oidx);
  a += *(const f32x4*)(h1 + oidx);
  a += *(const f32x4*)(eb + c4);
  uint2 o;
  o.x = pk2bf(a[0], a[1]);
  o.y = pk2bf(a[2], a[3]);
  *(uint2*)(q2b + oidx) = o;
}

extern "C" void kernel_launch(void* const* d_in, const int* in_sizes, int n_in,
                              void* d_out, int out_size, void* d_ws, size_t ws_size,
                              hipStream_t stream)
{
  const float* xt        = (const float*)d_in[0];
  const float* fc        = (const float*)d_in[1];
  const float* att_feats = (const float*)d_in[2];
  const float* p_att     = (const float*)d_in[3];
  const float* st_h      = (const float*)d_in[4];
  const float* st_c      = (const float*)d_in[5];
  const float* wi[3] = {(const float*)d_in[6],  (const float*)d_in[10], (const float*)d_in[14]};
  const float* bi[3] = {(const float*)d_in[7],  (const float*)d_in[11], (const float*)d_in[15]};
  const float* wh[3] = {(const float*)d_in[8],  (const float*)d_in[12], (const float*)d_in[16]};
  const float* bh[3] = {(const float*)d_in[9],  (const float*)d_in[13], (const float*)d_in[17]};
  const float* a_hw[2] = {(const float*)d_in[18], (const float*)d_in[22]};
  const float* a_hb[2] = {(const float*)d_in[19], (const float*)d_in[23]};
  const float* a_aw[2] = {(const float*)d_in[20], (const float*)d_in[24]};
  const float* a_ab[2] = {(const float*)d_in[21], (const float*)d_in[25]};
  const float* emb2_w = (const float*)d_in[26];
  const float* emb2_b = (const float*)d_in[27];

  float* out    = (float*)d_out;
  float* out_h2 = out;
  float* out_h  = out + 262144;
  float* out_c  = out + 262144 + 786432;
  const int BR = B_ * R_;

  const int ns = 4;

  float*  Sp    = (float*)d_ws;                       // ns x 1310720 f
  ushort* Xb0   = (ushort*)(Sp + (size_t)ns * 1310720);
  ushort* Xb1   = Xb0 + 786432;
  ushort* Xb2   = Xb1 + 786432;
  float*  attHp = (float*)(Xb2 + 786432);             // ns x 131072 f
  float*  sc    = attHp + (size_t)ns * 131072;        // 50176 f
  float*  q2p   = Sp;                                 // alias (Sp dead)
  ushort* q2b   = (ushort*)(Sp + (size_t)ns * 262144);

  dim3 blk(256);
  // LSTM GEMM: 128x64 tiles, XCD-grouped
  auto gemmL = [&](float* C, const ushort* Xb,
                   const float* W1, int ldw1, int K1,
                   const float* W2, int ldw2) {
    dim3 grid(2 * 80 * ns);
    hipLaunchKernelGGL(gemm_m128, grid, blk, 0, stream,
                       C, 5120, (size_t)256 * 5120, Xb, 3072,
                       W1, ldw1, K1, W2, ldw2, 3072, 80, ns);
  };
  // small GEMM: 64x64 tiles
  auto gemmS = [&](float* C, int ldc, const ushort* Xb, int ldx,
                   const float* W, int ldw, int K, int N) {
    dim3 grid((N / 64) * 4 * ns);
    hipLaunchKernelGGL(gemm_mfma, grid, blk, 0, stream,
                       C, ldc, (size_t)256 * ldc, Xb, ldx,
                       W, ldw, K, N / 64, ns);
  };

  // pack all fp32 activations -> bf16 X buffers (one launch)
  pack5<<<1280, 256, 0, stream>>>(xt, Xb0, fc, Xb0 + 1024, st_h, Xb0 + 2048,
                                  st_h + BR, Xb1 + 2048,
                                  st_h + 2 * BR, Xb2 + 2048);

  // ---- LSTM 0
  gemmL(Sp, Xb0, wi[0], 2048, 2048, wh[0], 1024);
  lstm_gates<<<256, 256, 0, stream>>>(Sp, ns, bi[0], bh[0], st_c,
                                      out_h, out_c, Xb1, nullptr);

  // ---- Attention 1 (query = h0 = Xb1[:, :1024])
  gemmS(attHp, 512, Xb1, 3072, a_hw[0], 1024, 1024, 512);
  att_scores<<<(B_ * L_) / 4, 256, 0, stream>>>(sc, p_att, attHp, ns,
                                                a_hb[0], a_aw[0], a_ab[0]);
  att_smw<<<B_ * 4, 256, 0, stream>>>(Xb1 + 1024, sc, att_feats);

  // ---- LSTM 1 (X = [h0, ar1, st_h1] = Xb1)
  gemmL(Sp, Xb1, wi[1], 2048, 2048, wh[1], 1024);
  lstm_gates<<<256, 256, 0, stream>>>(Sp, ns, bi[1], bh[1], st_c + BR,
                                      out_h + BR, out_c + BR, Xb2, nullptr);

  // ---- q2 = h1 + ar1 @ emb2_w^T + emb2_b
  gemmS(q2p, 1024, Xb1 + 1024, 3072, emb2_w, 1024, 1024, 1024);
  make_q2<<<256, 256, 0, stream>>>(q2b, q2p, ns, out_h + BR, emb2_b);

  // ---- Attention 2 (query = q2b)
  gemmS(attHp, 512, q2b, 1024, a_hw[1], 1024, 1024, 512);
  att_scores<<<(B_ * L_) / 4, 256, 0, stream>>>(sc, p_att, attHp, ns,
                                                a_hb[1], a_aw[1], a_ab[1]);
  att_smw<<<B_ * 4, 256, 0, stream>>>(Xb2 + 1024, sc, att_feats);

  // ---- LSTM 2 (X = [h1, ar2, st_h2] = Xb2)
  gemmL(Sp, Xb2, wi[2], 2048, 2048, wh[2], 1024);
  lstm_gates<<<256, 256, 0, stream>>>(Sp, ns, bi[2], bh[2], st_c + 2 * BR,
                                      out_h + 2 * BR, out_c + 2 * BR,
                                      nullptr, out_h2);
}

// Round 8
// 304.796 us; speedup vs baseline: 1.2855x; 1.2855x over previous
//
#include <hip/hip_runtime.h>
#include <hip/hip_bf16.h>
#include <cmath>

// ---------------------------------------------------------------------------
// StackAttCore: 3x LSTM + 2x additive attention. B=256 L=196 R=1024 A=512 E=1024
// Round 8: R5 GEMM structure (64x64 split-K ns=4, 5 blk/CU) + pack5 +
// att_smw rewritten with float4 feats loads (4 l-phases, LDS combine).
// ---------------------------------------------------------------------------

#define B_ 256
#define L_ 196
#define R_ 1024
#define A_ 512
#define E_ 1024

typedef __attribute__((ext_vector_type(8))) short bf16x8;
typedef __attribute__((ext_vector_type(4))) float f32x4;

__device__ inline ushort f2bf(float f) {
  __hip_bfloat16 h = __float2bfloat16(f);
  return *(ushort*)&h;
}
__device__ inline uint pk2bf(float lo, float hi) {
  float2 t; t.x = lo; t.y = hi;
  __hip_bfloat162 h = __float22bfloat162_rn(t);
  return *(uint*)&h;
}
__device__ inline float ftanh(float x) {
  float e = __expf(2.f * x);
  return 1.f - 2.f / (e + 1.f);
}

// ---------------------------------------------------------------------------
// Cpart[z][M,N] = Xb(bf16)[M, k0:k0+Ks] @ [W1|W2](fp32->bf16)[N, k0:k0+Ks]^T
// Tile 64x64, BK=64, 4 waves (2x2), 16x16x32 MFMA, XOR-swizzled LDS, dbuf.
// 1D grid, XCD-grouped decode. (R5-proven: 5 blocks/CU co-resident.)
// ---------------------------------------------------------------------------
__global__ __launch_bounds__(256) void gemm_mfma(
    float* __restrict__ C, int ldc, size_t pstride,
    const ushort* __restrict__ Xb, int ldx,
    const float* __restrict__ W1, int ldw1, int K1,
    const float* __restrict__ W2, int ldw2,
    int K, int nbn, int ns)
{
  __shared__ ushort lA[2][64 * 64];
  __shared__ ushort lB[2][64 * 64];
  const int tid = threadIdx.x;

  const int flat = blockIdx.x;
  const int xcd = flat & 7;
  const int j = flat >> 3;
  const int mB = j & 3;
  const int group = (j >> 2) * 8 + xcd;
  const int n0 = (group % nbn) * 64;
  const int z  = group / nbn;
  const int m0 = mB * 64;

  const int Ks = K / ns;
  const int k0 = z * Ks;
  C += (size_t)z * pstride;

  const int srow = tid >> 2;
  const int sq = tid & 3;
  const int wz0 = srow * 64 + (((sq * 2) ^ (srow & 7)) * 8);
  const int wz1 = srow * 64 + (((sq * 2 + 1) ^ (srow & 7)) * 8);

  const int lane = tid & 63;
  const int wid = tid >> 6;
  const int wr = wid >> 1, wc = wid & 1;
  const int l15 = lane & 15, l4 = lane >> 4;
  int aoff[2][2], boff[2][2];
#pragma unroll
  for (int m = 0; m < 2; m++)
#pragma unroll
    for (int s = 0; s < 2; s++) {
      int ra = wr * 32 + m * 16 + l15;
      int rb = wc * 32 + m * 16 + l15;
      int sl = s * 4 + l4;
      aoff[m][s] = ra * 64 + ((sl ^ (ra & 7)) * 8);
      boff[m][s] = rb * 64 + ((sl ^ (rb & 7)) * 8);
    }

  f32x4 zero = {0.f, 0.f, 0.f, 0.f};
  f32x4 acc[2][2];
  acc[0][0] = zero; acc[0][1] = zero; acc[1][0] = zero; acc[1][1] = zero;

  uint4 ax0, ax1;
  f32x4 bw[4];
  const int NT = Ks >> 6;

  auto g_load = [&](int kt) {
    const int kk = k0 + kt * 64;
    const ushort* ap = Xb + (size_t)(m0 + srow) * ldx + kk + sq * 16;
    ax0 = *(const uint4*)ap;
    ax1 = *(const uint4*)(ap + 8);
    const float* wp;
    if (kk < K1) wp = W1 + (size_t)(n0 + srow) * ldw1 + kk + sq * 16;
    else         wp = W2 + (size_t)(n0 + srow) * ldw2 + (kk - K1) + sq * 16;
    bw[0] = *(const f32x4*)wp;
    bw[1] = *(const f32x4*)(wp + 4);
    bw[2] = *(const f32x4*)(wp + 8);
    bw[3] = *(const f32x4*)(wp + 12);
  };
  auto s_write = [&](int buf) {
    *(uint4*)&lA[buf][wz0] = ax0;
    *(uint4*)&lA[buf][wz1] = ax1;
    uint4 b0, b1;
    b0.x = pk2bf(bw[0].x, bw[0].y); b0.y = pk2bf(bw[0].z, bw[0].w);
    b0.z = pk2bf(bw[1].x, bw[1].y); b0.w = pk2bf(bw[1].z, bw[1].w);
    b1.x = pk2bf(bw[2].x, bw[2].y); b1.y = pk2bf(bw[2].z, bw[2].w);
    b1.z = pk2bf(bw[3].x, bw[3].y); b1.w = pk2bf(bw[3].z, bw[3].w);
    *(uint4*)&lB[buf][wz0] = b0;
    *(uint4*)&lB[buf][wz1] = b1;
  };
  auto compute = [&](int buf) {
#pragma unroll
    for (int s = 0; s < 2; s++) {
      bf16x8 af0 = *(const bf16x8*)&lA[buf][aoff[0][s]];
      bf16x8 af1 = *(const bf16x8*)&lA[buf][aoff[1][s]];
      bf16x8 bf0 = *(const bf16x8*)&lB[buf][boff[0][s]];
      bf16x8 bf1 = *(const bf16x8*)&lB[buf][boff[1][s]];
      acc[0][0] = __builtin_amdgcn_mfma_f32_16x16x32_bf16(af0, bf0, acc[0][0], 0, 0, 0);
      acc[0][1] = __builtin_amdgcn_mfma_f32_16x16x32_bf16(af0, bf1, acc[0][1], 0, 0, 0);
      acc[1][0] = __builtin_amdgcn_mfma_f32_16x16x32_bf16(af1, bf0, acc[1][0], 0, 0, 0);
      acc[1][1] = __builtin_amdgcn_mfma_f32_16x16x32_bf16(af1, bf1, acc[1][1], 0, 0, 0);
    }
  };

  g_load(0);
  s_write(0);
  __syncthreads();
  int cur = 0;
  for (int kt = 0; kt < NT; kt++) {
    if (kt + 1 < NT) g_load(kt + 1);
    compute(cur);
    if (kt + 1 < NT) s_write(cur ^ 1);
    __syncthreads();
    cur ^= 1;
  }

#pragma unroll
  for (int m = 0; m < 2; m++)
#pragma unroll
    for (int n = 0; n < 2; n++) {
      const int col = n0 + wc * 32 + n * 16 + l15;
#pragma unroll
      for (int j2 = 0; j2 < 4; j2++) {
        const int row = m0 + wr * 32 + m * 16 + l4 * 4 + j2;
        C[(size_t)row * ldc + col] = acc[m][n][j2];
      }
    }
}

// pack 5 fp32 [256,1024] segments -> bf16 (dst row stride 3072)
__global__ __launch_bounds__(256) void pack5(
    const float* __restrict__ s0, ushort* __restrict__ d0,
    const float* __restrict__ s1, ushort* __restrict__ d1,
    const float* __restrict__ s2, ushort* __restrict__ d2,
    const float* __restrict__ s3, ushort* __restrict__ d3,
    const float* __restrict__ s4, ushort* __restrict__ d4)
{
  const int seg = blockIdx.x >> 8;
  const int row = blockIdx.x & 255;
  const int col = threadIdx.x * 4;
  const float* s;
  ushort* d;
  switch (seg) {
    case 0: s = s0; d = d0; break;
    case 1: s = s1; d = d1; break;
    case 2: s = s2; d = d2; break;
    case 3: s = s3; d = d3; break;
    default: s = s4; d = d4; break;
  }
  float4 v = *(const float4*)(s + (size_t)row * 1024 + col);
  uint2 o;
  o.x = pk2bf(v.x, v.y);
  o.y = pk2bf(v.z, v.w);
  *(uint2*)(d + (size_t)row * 3072 + col) = o;
}

// gates: sum ns partials, biases, activations -> h, c
__global__ __launch_bounds__(256) void lstm_gates(
    const float* __restrict__ Sp, int ns,
    const float* __restrict__ bi, const float* __restrict__ bh,
    const float* __restrict__ c_prev,
    float* __restrict__ h_out, float* __restrict__ c_out,
    ushort* __restrict__ hb16,
    float* __restrict__ h_out2)
{
  const int idx = blockIdx.x * 256 + threadIdx.x;
  const int b = idx >> 8;
  const int c4 = (idx & 255) * 4;
  const size_t base = (size_t)b * 5120 + c4;

  f32x4 g[5];
#pragma unroll
  for (int j = 0; j < 5; j++) g[j] = (f32x4){0.f, 0.f, 0.f, 0.f};
  for (int s = 0; s < ns; s++) {
    const float* sp = Sp + (size_t)s * 1310720 + base;
#pragma unroll
    for (int j = 0; j < 5; j++) g[j] += *(const f32x4*)(sp + j * 1024);
  }
#pragma unroll
  for (int j = 0; j < 5; j++) {
    g[j] += *(const f32x4*)(bi + j * 1024 + c4);
    g[j] += *(const f32x4*)(bh + j * 1024 + c4);
  }

  const int oidx = b * 1024 + c4;
  f32x4 cp = *(const f32x4*)(c_prev + oidx);
  f32x4 hv, cv;
#pragma unroll
  for (int i = 0; i < 4; i++) {
    float ig = 1.f / (1.f + __expf(-g[0][i]));
    float fg = 1.f / (1.f + __expf(-g[1][i]));
    float og = 1.f / (1.f + __expf(-g[2][i]));
    float it = fmaxf(g[3][i], g[4][i]);
    float c  = fg * cp[i] + ig * it;
    cv[i] = c;
    hv[i] = og * ftanh(c);
  }
  *(f32x4*)(h_out + oidx) = hv;
  *(f32x4*)(c_out + oidx) = cv;
  if (hb16) {
    uint2 o;
    o.x = pk2bf(hv[0], hv[1]);
    o.y = pk2bf(hv[2], hv[3]);
    *(uint2*)(hb16 + (size_t)b * 3072 + c4) = o;
  }
  if (h_out2) *(f32x4*)(h_out2 + oidx) = hv;
}

// scores[b,l] = sum_a tanh(p + sum_s attHp[s] + hb) * aw + ab ; wave per (b,l)
__global__ __launch_bounds__(256) void att_scores(
    float* __restrict__ scores,
    const float* __restrict__ p_att,
    const float* __restrict__ attHp, int ns,
    const float* __restrict__ hb,
    const float* __restrict__ aw,
    const float* __restrict__ ab)
{
  int wid = blockIdx.x * 4 + (threadIdx.x >> 6);
  if (wid >= B_ * L_) return;
  int lane = threadIdx.x & 63;
  int b = wid / L_;
  int l = wid % L_;
  const float* p = p_att + ((size_t)b * L_ + l) * A_;

  f32x4 q0 = {0.f, 0.f, 0.f, 0.f}, q1 = q0;
  for (int s = 0; s < ns; s++) {
    const float* qp = attHp + (size_t)s * 131072 + (size_t)b * A_ + lane * 8;
    q0 += *(const f32x4*)qp;
    q1 += *(const f32x4*)(qp + 4);
  }
  f32x4 p0 = *(const f32x4*)(p + lane * 8);
  f32x4 p1 = *(const f32x4*)(p + lane * 8 + 4);
  f32x4 h0 = *(const f32x4*)(hb + lane * 8);
  f32x4 h1 = *(const f32x4*)(hb + lane * 8 + 4);
  f32x4 w0 = *(const f32x4*)(aw + lane * 8);
  f32x4 w1 = *(const f32x4*)(aw + lane * 8 + 4);
  float part = 0.f;
#pragma unroll
  for (int i = 0; i < 4; i++) part += ftanh(p0[i] + q0[i] + h0[i]) * w0[i];
#pragma unroll
  for (int i = 0; i < 4; i++) part += ftanh(p1[i] + q1[i] + h1[i]) * w1[i];
#pragma unroll
  for (int off = 32; off > 0; off >>= 1) part += __shfl_down(part, off);
  if (lane == 0) scores[wid] = part + ab[0];
}

// ---------------------------------------------------------------------------
// fused softmax(196) + weighted sum over att_feats -> bf16 (stride 3072)
// block = (b, 256-col chunk); thread = (col-quad q = t&63, l-phase ph = t>>6).
// float4 feats loads: wave = 64 quads = 1KB contiguous per row; 4 rows in
// flight per wave x 16 waves/CU -> ~64KB/CU in flight (HBM-saturating).
// ---------------------------------------------------------------------------
__global__ __launch_bounds__(256) void att_smw(
    ushort* __restrict__ dst,
    const float* __restrict__ sc,
    const float* __restrict__ feats)
{
  const int b = blockIdx.x >> 2;
  const int dc = blockIdx.x & 3;
  const int t = threadIdx.x;
  const int q = t & 63;
  const int ph = t >> 6;
  __shared__ float red[256];
  __shared__ float wbuf[208];
  __shared__ f32x4 part[3][64];

  // softmax over sc[b, 0..195] -> wbuf
  float v = (t < L_) ? sc[b * L_ + t] : -1e30f;
  red[t] = v;
  __syncthreads();
  for (int s = 128; s > 0; s >>= 1) {
    if (t < s) red[t] = fmaxf(red[t], red[t + s]);
    __syncthreads();
  }
  float m = red[0];
  __syncthreads();
  float e = (t < L_) ? __expf(v - m) : 0.f;
  red[t] = e;
  __syncthreads();
  for (int s = 128; s > 0; s >>= 1) {
    if (t < s) red[t] += red[t + s];
    __syncthreads();
  }
  if (t < L_) wbuf[t] = e * (1.f / red[0]);
  __syncthreads();

  // weighted sum: phase ph covers l = ph, ph+4, ... (49 rows each)
  const int col = dc * 256 + q * 4;
  const float* f = feats + (size_t)b * L_ * R_ + col;
  f32x4 acc = {0.f, 0.f, 0.f, 0.f};
#pragma unroll 7
  for (int l = ph; l < L_; l += 4) {
    float wv = wbuf[l];
    f32x4 fv = *(const f32x4*)(f + (size_t)l * R_);
    acc += wv * fv;
  }
  if (ph != 0) part[ph - 1][q] = acc;
  __syncthreads();
  if (ph == 0) {
    acc += part[0][q];
    acc += part[1][q];
    acc += part[2][q];
    uint2 o;
    o.x = pk2bf(acc[0], acc[1]);
    o.y = pk2bf(acc[2], acc[3]);
    *(uint2*)(dst + (size_t)b * 3072 + col) = o;
  }
}

// q2b(bf16,[256,1024]) = sum_s q2p[s] + h1 + emb2_b
__global__ __launch_bounds__(256) void make_q2(
    ushort* __restrict__ q2b, const float* __restrict__ q2p, int ns,
    const float* __restrict__ h1, const float* __restrict__ eb)
{
  const int idx = blockIdx.x * 256 + threadIdx.x;
  const int b = idx >> 8;
  const int c4 = (idx & 255) * 4;
  const int oidx = b * 1024 + c4;
  f32x4 a = {0.f, 0.f, 0.f, 0.f};
  for (int s = 0; s < ns; s++)
    a += *(const f32x4*)(q2p + (size_t)s * 262144 + oidx);
  a += *(const f32x4*)(h1 + oidx);
  a += *(const f32x4*)(eb + c4);
  uint2 o;
  o.x = pk2bf(a[0], a[1]);
  o.y = pk2bf(a[2], a[3]);
  *(uint2*)(q2b + oidx) = o;
}

extern "C" void kernel_launch(void* const* d_in, const int* in_sizes, int n_in,
                              void* d_out, int out_size, void* d_ws, size_t ws_size,
                              hipStream_t stream)
{
  const float* xt        = (const float*)d_in[0];
  const float* fc        = (const float*)d_in[1];
  const float* att_feats = (const float*)d_in[2];
  const float* p_att     = (const float*)d_in[3];
  const float* st_h      = (const float*)d_in[4];
  const float* st_c      = (const float*)d_in[5];
  const float* wi[3] = {(const float*)d_in[6],  (const float*)d_in[10], (const float*)d_in[14]};
  const float* bi[3] = {(const float*)d_in[7],  (const float*)d_in[11], (const float*)d_in[15]};
  const float* wh[3] = {(const float*)d_in[8],  (const float*)d_in[12], (const float*)d_in[16]};
  const float* bh[3] = {(const float*)d_in[9],  (const float*)d_in[13], (const float*)d_in[17]};
  const float* a_hw[2] = {(const float*)d_in[18], (const float*)d_in[22]};
  const float* a_hb[2] = {(const float*)d_in[19], (const float*)d_in[23]};
  const float* a_aw[2] = {(const float*)d_in[20], (const float*)d_in[24]};
  const float* a_ab[2] = {(const float*)d_in[21], (const float*)d_in[25]};
  const float* emb2_w = (const float*)d_in[26];
  const float* emb2_b = (const float*)d_in[27];

  float* out    = (float*)d_out;
  float* out_h2 = out;
  float* out_h  = out + 262144;
  float* out_c  = out + 262144 + 786432;
  const int BR = B_ * R_;

  const int ns = 4;

  float*  Sp    = (float*)d_ws;                       // ns x 1310720 f
  ushort* Xb0   = (ushort*)(Sp + (size_t)ns * 1310720);
  ushort* Xb1   = Xb0 + 786432;
  ushort* Xb2   = Xb1 + 786432;
  float*  attHp = (float*)(Xb2 + 786432);             // ns x 131072 f
  float*  sc    = attHp + (size_t)ns * 131072;        // 50176 f
  float*  q2p   = Sp;                                 // alias (Sp dead)
  ushort* q2b   = (ushort*)(Sp + (size_t)ns * 262144);

  dim3 blk(256);
  auto gemmL = [&](float* C, const ushort* Xb,
                   const float* W1, int ldw1, int K1,
                   const float* W2, int ldw2) {
    dim3 grid(80 * 4 * ns);
    hipLaunchKernelGGL(gemm_mfma, grid, blk, 0, stream,
                       C, 5120, (size_t)256 * 5120, Xb, 3072,
                       W1, ldw1, K1, W2, ldw2, 3072, 80, ns);
  };
  auto gemmS = [&](float* C, int ldc, const ushort* Xb, int ldx,
                   const float* W, int ldw, int K, int N) {
    dim3 grid((N / 64) * 4 * ns);
    hipLaunchKernelGGL(gemm_mfma, grid, blk, 0, stream,
                       C, ldc, (size_t)256 * ldc, Xb, ldx,
                       W, ldw, K, nullptr, 0, K, N / 64, ns);
  };

  // pack all fp32 activations -> bf16 X buffers (one launch)
  pack5<<<1280, 256, 0, stream>>>(xt, Xb0, fc, Xb0 + 1024, st_h, Xb0 + 2048,
                                  st_h + BR, Xb1 + 2048,
                                  st_h + 2 * BR, Xb2 + 2048);

  // ---- LSTM 0
  gemmL(Sp, Xb0, wi[0], 2048, 2048, wh[0], 1024);
  lstm_gates<<<256, 256, 0, stream>>>(Sp, ns, bi[0], bh[0], st_c,
                                      out_h, out_c, Xb1, nullptr);

  // ---- Attention 1 (query = h0 = Xb1[:, :1024])
  gemmS(attHp, 512, Xb1, 3072, a_hw[0], 1024, 1024, 512);
  att_scores<<<(B_ * L_) / 4, 256, 0, stream>>>(sc, p_att, attHp, ns,
                                                a_hb[0], a_aw[0], a_ab[0]);
  att_smw<<<B_ * 4, 256, 0, stream>>>(Xb1 + 1024, sc, att_feats);

  // ---- LSTM 1 (X = [h0, ar1, st_h1] = Xb1)
  gemmL(Sp, Xb1, wi[1], 2048, 2048, wh[1], 1024);
  lstm_gates<<<256, 256, 0, stream>>>(Sp, ns, bi[1], bh[1], st_c + BR,
                                      out_h + BR, out_c + BR, Xb2, nullptr);

  // ---- q2 = h1 + ar1 @ emb2_w^T + emb2_b
  gemmS(q2p, 1024, Xb1 + 1024, 3072, emb2_w, 1024, 1024, 1024);
  make_q2<<<256, 256, 0, stream>>>(q2b, q2p, ns, out_h + BR, emb2_b);

  // ---- Attention 2 (query = q2b)
  gemmS(attHp, 512, q2b, 1024, a_hw[1], 1024, 1024, 512);
  att_scores<<<(B_ * L_) / 4, 256, 0, stream>>>(sc, p_att, attHp, ns,
                                                a_hb[1], a_aw[1], a_ab[1]);
  att_smw<<<B_ * 4, 256, 0, stream>>>(Xb2 + 1024, sc, att_feats);

  // ---- LSTM 2 (X = [h1, ar2, st_h2] = Xb2)
  gemmL(Sp, Xb2, wi[2], 2048, 2048, wh[2], 1024);
  lstm_gates<<<256, 256, 0, stream>>>(Sp, ns, bi[2], bh[2], st_c + 2 * BR,
                                      out_h + 2 * BR, out_c + 2 * BR,
                                      nullptr, out_h2);
}